// Round 1
// baseline (831.460 us; speedup 1.0000x reference)
//
#include <hip/hip_runtime.h>
#include <hip/hip_bf16.h>

#define DEV static __device__ __forceinline__

typedef __attribute__((ext_vector_type(8))) _Float16 half8;   // A/B frag: 8 fp16 = 4 VGPR
typedef __attribute__((ext_vector_type(4))) float f32x4;      // C/D frag

constexpr int Bc = 4, Tc = 2048, Dc = 2048, Hc = 16;          // HD = 128

DEV ushort f2h(float f) { _Float16 h = (_Float16)f; return __builtin_bit_cast(ushort, h); }
DEV float  h2f(ushort u) { return (float)__builtin_bit_cast(_Float16, u); }

DEV f32x4 MFMA(half8 a, half8 b, f32x4 c) {
  return __builtin_amdgcn_mfma_f32_16x16x32_f16(a, b, c, 0, 0, 0);
}

DEV void async_cp16(void* lds, const void* g) {
  __builtin_amdgcn_global_load_lds((const __attribute__((address_space(1))) void*)g,
                                   (__attribute__((address_space(3))) void*)lds,
                                   16, 0, 0);
}

// ---------------- f32 -> fp16 convert ----------------
__global__ __launch_bounds__(256) void cvt(const float* __restrict__ in,
                                           ushort* __restrict__ out, int n4) {
  const int i = blockIdx.x * 256 + threadIdx.x;
  if (i >= n4) return;
  const float4 v = ((const float4*)in)[i];
  ushort4 o;
  o.x = f2h(v.x); o.y = f2h(v.y); o.z = f2h(v.z); o.w = f2h(v.w);
  ((ushort4*)out)[i] = o;
}

// ---------------- GEMM: C[m][n] = sum_k A[m][k] * W[n][k] ----------------
// A [8192][2048] fp16, W [2048][2048] fp16 (nn.Linear: y = x @ W^T).
// 128x128 tile, BK=32, 4 waves (2x2), global_load_lds staging, 16 MFMA/K-step.
template <typename OutT>
__global__ __launch_bounds__(256) void gemm_bt(const ushort* __restrict__ A,
                                               const ushort* __restrict__ Bw,
                                               OutT* __restrict__ C) {
  __shared__ ushort As[128 * 32];
  __shared__ ushort Bs[128 * 32];
  const int tid = threadIdx.x;
  const int lane = tid & 63, wid = tid >> 6;
  const int g = lane >> 4, q16 = lane & 15;
  const int wm = wid >> 1, wn = wid & 1;
  const int bm = blockIdx.y, bn = blockIdx.x;
  const ushort* Ab = A + (size_t)bm * 128 * Dc;
  const ushort* Bb = Bw + (size_t)bn * 128 * Dc;

  f32x4 acc[4][4] = {};

  for (int k0 = 0; k0 < Dc; k0 += 32) {
    __syncthreads();
#pragma unroll
    for (int q = 0; q < 2; ++q) {
      const int c = q * 256 + tid;            // chunk id: 16B each, row = c/4, col = (c%4)*8
      const int row = c >> 2, col = (c & 3) << 3;
      const int ldsbase = (q * 256 + wid * 64) * 8;  // wave-uniform dest (lane*16B implicit)
      async_cp16(&As[ldsbase], Ab + (size_t)row * Dc + k0 + col);
      async_cp16(&Bs[ldsbase], Bb + (size_t)row * Dc + k0 + col);
    }
    __syncthreads();   // drains vmcnt before barrier (compiler-emitted)
    half8 a[4], b[4];
#pragma unroll
    for (int i = 0; i < 4; ++i)
      a[i] = *(const half8*)&As[(wm * 64 + i * 16 + q16) * 32 + g * 8];
#pragma unroll
    for (int j = 0; j < 4; ++j)
      b[j] = *(const half8*)&Bs[(wn * 64 + j * 16 + q16) * 32 + g * 8];
#pragma unroll
    for (int i = 0; i < 4; ++i)
#pragma unroll
      for (int j = 0; j < 4; ++j)
        acc[i][j] = MFMA(a[i], b[j], acc[i][j]);
  }

  // D frag: col = lane&15 (n), row = g*4 + r (m)
  const int m00 = bm * 128 + wm * 64 + g * 4;
  const int n0 = bn * 128 + wn * 64 + q16;
#pragma unroll
  for (int i = 0; i < 4; ++i)
#pragma unroll
    for (int j = 0; j < 4; ++j) {
      const int m0 = m00 + i * 16;
      const int n = n0 + j * 16;
#pragma unroll
      for (int r = 0; r < 4; ++r) {
        const float v = acc[i][j][r];
        if constexpr (sizeof(OutT) == 2)
          C[(size_t)(m0 + r) * Dc + n] = (OutT)f2h(v);
        else
          C[(size_t)(m0 + r) * Dc + n] = (OutT)v;
      }
    }
}

// ---------------- RoPE in-place on [B,T,H,128] fp16 ----------------
__global__ __launch_bounds__(256) void rope(ushort* __restrict__ X,
                                            const float* __restrict__ cs,
                                            const float* __restrict__ sn) {
  const int tid = blockIdx.x * 256 + threadIdx.x;
  const int row = tid >> 4;              // (b*T + t)*H + h
  const int jq = (tid & 15) << 2;        // j in [0,64) step 4
  const int t = (row >> 4) & (Tc - 1);
  ushort* base = X + (size_t)row * 128;
  const ushort4 lo = *(const ushort4*)(base + jq);
  const ushort4 hi = *(const ushort4*)(base + 64 + jq);
  const float4 c4 = *(const float4*)(cs + t * 128 + jq);   // cos[t][j]==cos[t][j+64]
  const float4 s4 = *(const float4*)(sn + t * 128 + jq);
  const float xl[4] = {h2f(lo.x), h2f(lo.y), h2f(lo.z), h2f(lo.w)};
  const float xh[4] = {h2f(hi.x), h2f(hi.y), h2f(hi.z), h2f(hi.w)};
  const float cc[4] = {c4.x, c4.y, c4.z, c4.w};
  const float ss[4] = {s4.x, s4.y, s4.z, s4.w};
  ushort4 olo, ohi;
  ushort* po = (ushort*)&olo;
  ushort* ph = (ushort*)&ohi;
#pragma unroll
  for (int k = 0; k < 4; ++k) {
    po[k] = f2h(xl[k] * cc[k] - xh[k] * ss[k]);
    ph[k] = f2h(xh[k] * cc[k] + xl[k] * ss[k]);
  }
  *(ushort4*)(base + jq) = olo;
  *(ushort4*)(base + 64 + jq) = ohi;
}

// ---------------- causal flash attention ----------------
// grid (16, 64): x = q-tile (reversed for load balance), y = b*16+h.
// Block: 128 q-rows, 4 waves x 32 rows. Swapped QK^T (mfma(K,Q)) -> S^T;
// per-wave P LDS buffer re-fragments P for PV (O^T = V^T P^T).
__global__ __launch_bounds__(256) void attn(const ushort* __restrict__ Q,
                                            const ushort* __restrict__ K,
                                            const ushort* __restrict__ V,
                                            ushort* __restrict__ O) {
  __shared__ ushort Ks[64 * 128];      // [kv][d], XOR-swizzled rows
  __shared__ ushort Vt[128 * 64];      // [d][kv], XOR-swizzled rows
  __shared__ ushort Pt[4][32 * 64];    // per-wave [q][kv], XOR-swizzled rows

  const int tid = threadIdx.x;
  const int lane = tid & 63, wid = tid >> 6;
  const int g = lane >> 4, q16 = lane & 15;
  const int bh = blockIdx.y;
  const int b = bh >> 4, h = bh & 15;
  const int q0 = (int)(gridDim.x - 1 - blockIdx.x) * 128;
  const size_t headbase = ((size_t)b * Tc * Hc + h) * 128;  // elem offset of (b,0,h,0); t-stride = 2048
  const int qrow = q0 + wid * 32;
  const float SCL2 = 0.12751743f;      // log2(e)/sqrt(128)

  // Q fragments to registers (B-op: col=q=lane&15, k=d=g*8+j)
  half8 qreg[2][4];
#pragma unroll
  for (int qf = 0; qf < 2; ++qf)
#pragma unroll
    for (int ds = 0; ds < 4; ++ds)
      qreg[qf][ds] = *(const half8*)(Q + headbase +
                     (size_t)(qrow + qf * 16 + q16) * Dc + ds * 32 + g * 8);

  f32x4 oacc[8][2] = {};               // O^T frags: row=d (g*4+r), col=q (lane&15)
  float m_[2] = {-1e30f, -1e30f};
  float l_[2] = {0.f, 0.f};

  const int nt = q0 / 64 + 2;
  for (int kt = 0; kt < nt; ++kt) {
    __syncthreads();
    const int kv0 = kt * 64;
    // stage K tile [64][128], swizzle elem ^= (kv&7)<<3
    const ushort* Kb = K + headbase + (size_t)kv0 * Dc;
#pragma unroll
    for (int i = 0; i < 4; ++i) {
      const int c = i * 256 + tid;
      const int kv = c >> 4, dc8 = (c & 15) << 3;
      const uint4 v = *(const uint4*)(Kb + (size_t)kv * Dc + dc8);
      *(uint4*)&Ks[(kv * 128 + dc8) ^ ((kv & 7) << 3)] = v;
    }
    // stage V transposed: Vt[d][kv], pack kv-pairs into dwords
    const ushort* Vb = V + headbase + (size_t)kv0 * Dc;
#pragma unroll
    for (int i = 0; i < 2; ++i) {
      const int kvp = i * 16 + (lane >> 2);
      const int dc = wid * 4 + (lane & 3);
      const ushort* p0 = Vb + (size_t)(2 * kvp) * Dc + dc * 8;
      const uint4 r0 = *(const uint4*)p0;
      const uint4 r1 = *(const uint4*)(p0 + Dc);
      const ushort* e0 = (const ushort*)&r0;
      const ushort* e1 = (const ushort*)&r1;
#pragma unroll
      for (int j = 0; j < 8; ++j) {
        const int d = dc * 8 + j;
        const unsigned w = (unsigned)e0[j] | ((unsigned)e1[j] << 16);
        *(unsigned*)&Vt[(d * 64 + 2 * kvp) ^ ((d & 7) << 3)] = w;
      }
    }
    __syncthreads();

    if (kv0 <= qrow + 31) {
      // S^T = K Q^T : A-op = K rows (kv=lane&15 block), B-op = Q
      f32x4 s[4][2] = {};
#pragma unroll
      for (int ds = 0; ds < 4; ++ds) {
        half8 kf[4];
#pragma unroll
        for (int kvf = 0; kvf < 4; ++kvf) {
          const int kv = kvf * 16 + q16;
          kf[kvf] = *(const half8*)&Ks[(kv * 128 + ds * 32 + g * 8) ^ ((kv & 7) << 3)];
        }
#pragma unroll
        for (int kvf = 0; kvf < 4; ++kvf)
#pragma unroll
          for (int qf = 0; qf < 2; ++qf)
            s[kvf][qf] = MFMA(kf[kvf], qreg[qf][ds], s[kvf][qf]);
      }
      // causal mask + per-q running max (q = lane&15 + 16*qf; kv = kv0+kvf*16+g*4+r)
      const bool notfull = (kv0 + 63) > qrow;
      float pmax[2] = {-1e30f, -1e30f};
#pragma unroll
      for (int qf = 0; qf < 2; ++qf) {
        const int qg = qrow + qf * 16 + q16;
#pragma unroll
        for (int kvf = 0; kvf < 4; ++kvf)
#pragma unroll
          for (int r = 0; r < 4; ++r) {
            float v = s[kvf][qf][r];
            if (notfull && (kv0 + kvf * 16 + g * 4 + r) > qg) v = -1e30f;
            s[kvf][qf][r] = v;
            pmax[qf] = fmaxf(pmax[qf], v);
          }
      }
#pragma unroll
      for (int qf = 0; qf < 2; ++qf) {
        pmax[qf] = fmaxf(pmax[qf], __shfl_xor(pmax[qf], 16));
        pmax[qf] = fmaxf(pmax[qf], __shfl_xor(pmax[qf], 32));
      }
      float alpha[2];
      ushort* Ptw = Pt[wid];
#pragma unroll
      for (int qf = 0; qf < 2; ++qf) {
        const float mn = fmaxf(m_[qf], pmax[qf]);
        alpha[qf] = __builtin_exp2f((m_[qf] - mn) * SCL2);
        m_[qf] = mn;
        float lsum = 0.f;
#pragma unroll
        for (int kvf = 0; kvf < 4; ++kvf) {
          const float p0 = __builtin_exp2f((s[kvf][qf][0] - mn) * SCL2);
          const float p1 = __builtin_exp2f((s[kvf][qf][1] - mn) * SCL2);
          const float p2 = __builtin_exp2f((s[kvf][qf][2] - mn) * SCL2);
          const float p3 = __builtin_exp2f((s[kvf][qf][3] - mn) * SCL2);
          lsum += (p0 + p1) + (p2 + p3);
          uint2 pk;
          pk.x = (unsigned)f2h(p0) | ((unsigned)f2h(p1) << 16);
          pk.y = (unsigned)f2h(p2) | ((unsigned)f2h(p3) << 16);
          const int row = qf * 16 + q16;
          *(uint2*)&Ptw[(row * 64 + kvf * 16 + g * 4) ^ ((row & 7) << 3)] = pk;
        }
        lsum += __shfl_xor(lsum, 16);
        lsum += __shfl_xor(lsum, 32);
        l_[qf] = l_[qf] * alpha[qf] + lsum;
      }
#pragma unroll
      for (int df = 0; df < 8; ++df)
#pragma unroll
        for (int qf = 0; qf < 2; ++qf)
          oacc[df][qf] *= alpha[qf];
      // O^T += V^T P^T  (A-op = Vt rows d, B-op = P^T cols q)
#pragma unroll
      for (int c = 0; c < 2; ++c) {
        half8 pb[2];
#pragma unroll
        for (int qf = 0; qf < 2; ++qf) {
          const int row = qf * 16 + q16;
          pb[qf] = *(const half8*)&Ptw[(row * 64 + c * 32 + g * 8) ^ ((row & 7) << 3)];
        }
#pragma unroll
        for (int df = 0; df < 8; ++df) {
          const int d = df * 16 + q16;
          const half8 vf = *(const half8*)&Vt[(d * 64 + c * 32 + g * 8) ^ ((d & 7) << 3)];
#pragma unroll
          for (int qf = 0; qf < 2; ++qf)
            oacc[df][qf] = MFMA(vf, pb[qf], oacc[df][qf]);
        }
      }
    }
  }
  // epilogue: O[b][t][h][d] fp16; lane writes 4 consecutive d per frag
#pragma unroll
  for (int qf = 0; qf < 2; ++qf) {
    const float inv = 1.0f / l_[qf];
    const int t = qrow + qf * 16 + q16;
#pragma unroll
    for (int df = 0; df < 8; ++df) {
      const f32x4 v = oacc[df][qf];
      ushort4 o;
      o.x = f2h(v[0] * inv); o.y = f2h(v[1] * inv);
      o.z = f2h(v[2] * inv); o.w = f2h(v[3] * inv);
      *(ushort4*)(O + headbase + (size_t)t * Dc + df * 16 + g * 4) = o;
    }
  }
}

extern "C" void kernel_launch(void* const* d_in, const int* in_sizes, int n_in,
                              void* d_out, int out_size, void* d_ws, size_t ws_size,
                              hipStream_t stream) {
  (void)in_sizes; (void)n_in; (void)out_size; (void)ws_size;
  const float* x  = (const float*)d_in[0];
  const float* cs = (const float*)d_in[1];
  const float* sn = (const float*)d_in[2];
  // d_in[3] = mask (unused: causal handled analytically)
  const float* Wq = (const float*)d_in[4];
  const float* Wk = (const float*)d_in[5];
  const float* Wv = (const float*)d_in[6];
  const float* Wo = (const float*)d_in[7];
  float* out = (float*)d_out;

  char* ws = (char*)d_ws;
  const size_t MB = 1024 * 1024;
  ushort* xb  = (ushort*)(ws);            // 32MB x fp16; reused as attention output O
  ushort* wqb = (ushort*)(ws + 32 * MB);  // 8MB each
  ushort* wkb = (ushort*)(ws + 40 * MB);
  ushort* wvb = (ushort*)(ws + 48 * MB);
  ushort* wob = (ushort*)(ws + 56 * MB);
  ushort* Qr  = (ushort*)(ws + 64 * MB);  // 32MB each, [B,T,H,128] fp16
  ushort* Kr  = (ushort*)(ws + 96 * MB);
  ushort* Vr  = (ushort*)(ws + 128 * MB); // end: 160MB

  cvt<<<16384, 256, 0, stream>>>(x, xb, 4194304);
  cvt<<<4096, 256, 0, stream>>>(Wq, wqb, 1048576);
  cvt<<<4096, 256, 0, stream>>>(Wk, wkb, 1048576);
  cvt<<<4096, 256, 0, stream>>>(Wv, wvb, 1048576);
  cvt<<<4096, 256, 0, stream>>>(Wo, wob, 1048576);

  const dim3 gg(16, 64);
  gemm_bt<ushort><<<gg, 256, 0, stream>>>(xb, wqb, Qr);
  gemm_bt<ushort><<<gg, 256, 0, stream>>>(xb, wkb, Kr);
  gemm_bt<ushort><<<gg, 256, 0, stream>>>(xb, wvb, Vr);

  rope<<<8192, 256, 0, stream>>>(Qr, cs, sn);
  rope<<<8192, 256, 0, stream>>>(Kr, cs, sn);

  attn<<<dim3(16, 64), 256, 0, stream>>>(Qr, Kr, Vr, xb);

  gemm_bt<float><<<gg, 256, 0, stream>>>(xb, wob, out);
}

// Round 2
// 800.979 us; speedup vs baseline: 1.0381x; 1.0381x over previous
//
#include <hip/hip_runtime.h>
#include <hip/hip_bf16.h>

#define DEV static __device__ __forceinline__

typedef __attribute__((ext_vector_type(8))) _Float16 half8;   // A/B frag: 8 fp16 = 4 VGPR
typedef __attribute__((ext_vector_type(4))) float f32x4;      // C/D frag

constexpr int Bc = 4, Tc = 2048, Dc = 2048, Hc = 16;          // HD = 128

DEV ushort f2h(float f) { _Float16 h = (_Float16)f; return __builtin_bit_cast(ushort, h); }
DEV float  h2f(ushort u) { return (float)__builtin_bit_cast(_Float16, u); }

DEV f32x4 MFMA(half8 a, half8 b, f32x4 c) {
  return __builtin_amdgcn_mfma_f32_16x16x32_f16(a, b, c, 0, 0, 0);
}

DEV void async_cp16(void* lds, const void* g) {
  __builtin_amdgcn_global_load_lds((const __attribute__((address_space(1))) void*)g,
                                   (__attribute__((address_space(3))) void*)lds,
                                   16, 0, 0);
}

// ---------------- f32 -> fp16 convert ----------------
__global__ __launch_bounds__(256) void cvt(const float* __restrict__ in,
                                           ushort* __restrict__ out, int n4) {
  const int i = blockIdx.x * 256 + threadIdx.x;
  if (i >= n4) return;
  const float4 v = ((const float4*)in)[i];
  ushort4 o;
  o.x = f2h(v.x); o.y = f2h(v.y); o.z = f2h(v.z); o.w = f2h(v.w);
  ((ushort4*)out)[i] = o;
}

// ---------------- GEMM: C[m][n] = sum_k A[m][k] * W[n][k] ----------------
// 128x128 tile, BK=32, 4 waves (2x2), global_load_lds staging, 16 MFMA/K-step.
template <typename OutT>
__global__ __launch_bounds__(256) void gemm_bt(const ushort* __restrict__ A,
                                               const ushort* __restrict__ Bw,
                                               OutT* __restrict__ C) {
  __shared__ ushort As[128 * 32];
  __shared__ ushort Bs[128 * 32];
  const int tid = threadIdx.x;
  const int lane = tid & 63, wid = tid >> 6;
  const int g = lane >> 4, q16 = lane & 15;
  const int wm = wid >> 1, wn = wid & 1;
  const int bm = blockIdx.y, bn = blockIdx.x;
  const ushort* Ab = A + (size_t)bm * 128 * Dc;
  const ushort* Bb = Bw + (size_t)bn * 128 * Dc;

  f32x4 acc[4][4] = {};

  for (int k0 = 0; k0 < Dc; k0 += 32) {
    __syncthreads();
#pragma unroll
    for (int q = 0; q < 2; ++q) {
      const int c = q * 256 + tid;
      const int row = c >> 2, col = (c & 3) << 3;
      const int ldsbase = (q * 256 + wid * 64) * 8;
      async_cp16(&As[ldsbase], Ab + (size_t)row * Dc + k0 + col);
      async_cp16(&Bs[ldsbase], Bb + (size_t)row * Dc + k0 + col);
    }
    __syncthreads();
    half8 a[4], b[4];
#pragma unroll
    for (int i = 0; i < 4; ++i)
      a[i] = *(const half8*)&As[(wm * 64 + i * 16 + q16) * 32 + g * 8];
#pragma unroll
    for (int j = 0; j < 4; ++j)
      b[j] = *(const half8*)&Bs[(wn * 64 + j * 16 + q16) * 32 + g * 8];
#pragma unroll
    for (int i = 0; i < 4; ++i)
#pragma unroll
      for (int j = 0; j < 4; ++j)
        acc[i][j] = MFMA(a[i], b[j], acc[i][j]);
  }

  const int m00 = bm * 128 + wm * 64 + g * 4;
  const int n0 = bn * 128 + wn * 64 + q16;
#pragma unroll
  for (int i = 0; i < 4; ++i)
#pragma unroll
    for (int j = 0; j < 4; ++j) {
      const int m0 = m00 + i * 16;
      const int n = n0 + j * 16;
#pragma unroll
      for (int r = 0; r < 4; ++r) {
        const float v = acc[i][j][r];
        if constexpr (sizeof(OutT) == 2)
          C[(size_t)(m0 + r) * Dc + n] = (OutT)f2h(v);
        else
          C[(size_t)(m0 + r) * Dc + n] = (OutT)v;
      }
    }
}

// ---------------- RoPE in-place on [B,T,H,128] fp16 ----------------
__global__ __launch_bounds__(256) void rope(ushort* __restrict__ X,
                                            const float* __restrict__ cs,
                                            const float* __restrict__ sn) {
  const int tid = blockIdx.x * 256 + threadIdx.x;
  const int row = tid >> 4;
  const int jq = (tid & 15) << 2;
  const int t = (row >> 4) & (Tc - 1);
  ushort* base = X + (size_t)row * 128;
  const ushort4 lo = *(const ushort4*)(base + jq);
  const ushort4 hi = *(const ushort4*)(base + 64 + jq);
  const float4 c4 = *(const float4*)(cs + t * 128 + jq);
  const float4 s4 = *(const float4*)(sn + t * 128 + jq);
  const float xl[4] = {h2f(lo.x), h2f(lo.y), h2f(lo.z), h2f(lo.w)};
  const float xh[4] = {h2f(hi.x), h2f(hi.y), h2f(hi.z), h2f(hi.w)};
  const float cc[4] = {c4.x, c4.y, c4.z, c4.w};
  const float ss[4] = {s4.x, s4.y, s4.z, s4.w};
  ushort4 olo, ohi;
  ushort* po = (ushort*)&olo;
  ushort* ph = (ushort*)&ohi;
#pragma unroll
  for (int k = 0; k < 4; ++k) {
    po[k] = f2h(xl[k] * cc[k] - xh[k] * ss[k]);
    ph[k] = f2h(xh[k] * cc[k] + xl[k] * ss[k]);
  }
  *(ushort4*)(base + jq) = olo;
  *(ushort4*)(base + 64 + jq) = ohi;
}

// ---------------- causal flash attention (paired q-tiles, dbuf LDS) ------
// grid (8, 64): block processes q-tiles {15-bx, bx} -> uniform 34 kv-tile
// iterations per block; 512 blocks = exactly 2 blocks/CU residency.
// Double-buffered K/Vt, T14 async-STAGE (loads early, ds_write after compute),
// raw s_barrier (keeps vmcnt in flight across the barrier).
__global__ __launch_bounds__(256, 2) void attn(const ushort* __restrict__ Q,
                                               const ushort* __restrict__ K,
                                               const ushort* __restrict__ V,
                                               ushort* __restrict__ O) {
  __shared__ ushort Ks[2][64 * 128];   // [kv][d], XOR-swizzled rows
  __shared__ ushort Vt[2][128 * 64];   // [d][kv], XOR-swizzled rows
  __shared__ ushort Pt[4][32 * 64];    // per-wave [q][kv]

  const int tid = threadIdx.x;
  const int lane = tid & 63, wid = tid >> 6;
  const int g = lane >> 4, q16 = lane & 15;
  const int bh = blockIdx.y;
  const int b = bh >> 4, h = bh & 15;
  const size_t headbase = ((size_t)b * Tc * Hc + h) * 128;  // t-stride = 2048
  const float SCL2 = 0.12751743f;      // log2(e)/sqrt(128)

  uint4 kreg[4], vreg[4];

#define LOADKV(KT) do {                                                        \
    const ushort* Kb_ = K + headbase + (size_t)(KT) * 64 * Dc;                 \
    const ushort* Vb_ = V + headbase + (size_t)(KT) * 64 * Dc;                 \
    _Pragma("unroll") for (int i_ = 0; i_ < 4; ++i_) {                         \
      const int c_ = i_ * 256 + tid;                                           \
      kreg[i_] = *(const uint4*)(Kb_ + (size_t)(c_ >> 4) * Dc +                \
                                 ((c_ & 15) << 3));                            \
    }                                                                          \
    _Pragma("unroll") for (int i_ = 0; i_ < 2; ++i_) {                         \
      const int kvp_ = i_ * 16 + (lane >> 2);                                  \
      const int dc_ = wid * 4 + (lane & 3);                                    \
      const ushort* p0_ = Vb_ + (size_t)(2 * kvp_) * Dc + dc_ * 8;             \
      vreg[2 * i_] = *(const uint4*)p0_;                                       \
      vreg[2 * i_ + 1] = *(const uint4*)(p0_ + Dc);                            \
    }                                                                          \
  } while (0)

#define WRITEKV(BUF) do {                                                      \
    _Pragma("unroll") for (int i_ = 0; i_ < 4; ++i_) {                         \
      const int c_ = i_ * 256 + tid;                                           \
      const int kv_ = c_ >> 4, dc8_ = (c_ & 15) << 3;                          \
      *(uint4*)&Ks[BUF][(kv_ * 128 + dc8_) ^ ((kv_ & 7) << 3)] = kreg[i_];     \
    }                                                                          \
    _Pragma("unroll") for (int i_ = 0; i_ < 2; ++i_) {                         \
      const int kvp_ = i_ * 16 + (lane >> 2);                                  \
      const int dc_ = wid * 4 + (lane & 3);                                    \
      const ushort* e0_ = (const ushort*)&vreg[2 * i_];                        \
      const ushort* e1_ = (const ushort*)&vreg[2 * i_ + 1];                    \
      _Pragma("unroll") for (int j_ = 0; j_ < 8; ++j_) {                       \
        const int d_ = dc_ * 8 + j_;                                           \
        const unsigned w_ = (unsigned)e0_[j_] | ((unsigned)e1_[j_] << 16);     \
        *(unsigned*)&Vt[BUF][(d_ * 64 + 2 * kvp_) ^ ((d_ & 7) << 3)] = w_;     \
      }                                                                        \
    }                                                                          \
  } while (0)

#pragma unroll 1
  for (int half = 0; half < 2; ++half) {
    const int q0 = (half ? (int)blockIdx.x : 15 - (int)blockIdx.x) * 128;
    const int qrow = q0 + wid * 32;
    const int nt = q0 / 64 + 2;

    // Q fragments (B-op: col=q=lane&15, k=d=g*8+j)
    half8 qreg[2][4];
#pragma unroll
    for (int qf = 0; qf < 2; ++qf)
#pragma unroll
      for (int ds = 0; ds < 4; ++ds)
        qreg[qf][ds] = *(const half8*)(Q + headbase +
                       (size_t)(qrow + qf * 16 + q16) * Dc + ds * 32 + g * 8);

    f32x4 oacc[8][2] = {};             // O^T frags: row=d (g*4+r), col=q
    float m_[2] = {-1e30f, -1e30f};
    float l_[2] = {0.f, 0.f};

    LOADKV(0);
    asm volatile("s_waitcnt lgkmcnt(0)" ::: "memory");
    __builtin_amdgcn_s_barrier();      // prev half's readers of buf0 are done
    WRITEKV(0);

#pragma unroll 1
    for (int kt = 0; kt < nt; ++kt) {
      const int cur = kt & 1;
      const int kv0 = kt * 64;
      if (kt + 1 < nt) LOADKV(kt + 1);           // issue early, stays in flight
      asm volatile("s_waitcnt lgkmcnt(0)" ::: "memory");
      __builtin_amdgcn_s_barrier();              // buf[cur] ready; vmcnt NOT drained

      if (kv0 <= qrow + 31) {
        const ushort* Ksb = Ks[cur];
        const ushort* Vtb = Vt[cur];
        // S^T = K Q^T
        f32x4 s[4][2] = {};
        __builtin_amdgcn_s_setprio(1);
#pragma unroll
        for (int ds = 0; ds < 4; ++ds) {
          half8 kf[4];
#pragma unroll
          for (int kvf = 0; kvf < 4; ++kvf) {
            const int kv = kvf * 16 + q16;
            kf[kvf] = *(const half8*)&Ksb[(kv * 128 + ds * 32 + g * 8) ^ ((kv & 7) << 3)];
          }
#pragma unroll
          for (int kvf = 0; kvf < 4; ++kvf)
#pragma unroll
            for (int qf = 0; qf < 2; ++qf)
              s[kvf][qf] = MFMA(kf[kvf], qreg[qf][ds], s[kvf][qf]);
        }
        __builtin_amdgcn_s_setprio(0);
        // causal mask + running max (q = lane&15 + 16*qf; kv = kv0+kvf*16+g*4+r)
        const bool notfull = (kv0 + 63) > qrow;
        float pmax[2] = {-1e30f, -1e30f};
#pragma unroll
        for (int qf = 0; qf < 2; ++qf) {
          const int qg = qrow + qf * 16 + q16;
#pragma unroll
          for (int kvf = 0; kvf < 4; ++kvf)
#pragma unroll
            for (int r = 0; r < 4; ++r) {
              float v = s[kvf][qf][r];
              if (notfull && (kv0 + kvf * 16 + g * 4 + r) > qg) v = -1e30f;
              s[kvf][qf][r] = v;
              pmax[qf] = fmaxf(pmax[qf], v);
            }
        }
#pragma unroll
        for (int qf = 0; qf < 2; ++qf) {
          pmax[qf] = fmaxf(pmax[qf], __shfl_xor(pmax[qf], 16));
          pmax[qf] = fmaxf(pmax[qf], __shfl_xor(pmax[qf], 32));
        }
        float alpha[2];
        ushort* Ptw = Pt[wid];
#pragma unroll
        for (int qf = 0; qf < 2; ++qf) {
          const float mn = fmaxf(m_[qf], pmax[qf]);
          alpha[qf] = __builtin_exp2f((m_[qf] - mn) * SCL2);
          m_[qf] = mn;
          float lsum = 0.f;
#pragma unroll
          for (int kvf = 0; kvf < 4; ++kvf) {
            const float p0 = __builtin_exp2f((s[kvf][qf][0] - mn) * SCL2);
            const float p1 = __builtin_exp2f((s[kvf][qf][1] - mn) * SCL2);
            const float p2 = __builtin_exp2f((s[kvf][qf][2] - mn) * SCL2);
            const float p3 = __builtin_exp2f((s[kvf][qf][3] - mn) * SCL2);
            lsum += (p0 + p1) + (p2 + p3);
            uint2 pk;
            pk.x = (unsigned)f2h(p0) | ((unsigned)f2h(p1) << 16);
            pk.y = (unsigned)f2h(p2) | ((unsigned)f2h(p3) << 16);
            const int row = qf * 16 + q16;
            *(uint2*)&Ptw[(row * 64 + kvf * 16 + g * 4) ^ ((row & 7) << 3)] = pk;
          }
          lsum += __shfl_xor(lsum, 16);
          lsum += __shfl_xor(lsum, 32);
          l_[qf] = l_[qf] * alpha[qf] + lsum;
        }
#pragma unroll
        for (int df = 0; df < 8; ++df)
#pragma unroll
          for (int qf = 0; qf < 2; ++qf)
            oacc[df][qf] *= alpha[qf];
        // O^T += V^T P^T
        __builtin_amdgcn_s_setprio(1);
#pragma unroll
        for (int c = 0; c < 2; ++c) {
          half8 pb[2];
#pragma unroll
          for (int qf = 0; qf < 2; ++qf) {
            const int row = qf * 16 + q16;
            pb[qf] = *(const half8*)&Ptw[(row * 64 + c * 32 + g * 8) ^ ((row & 7) << 3)];
          }
#pragma unroll
          for (int df = 0; df < 8; ++df) {
            const int d = df * 16 + q16;
            const half8 vf = *(const half8*)&Vtb[(d * 64 + c * 32 + g * 8) ^ ((d & 7) << 3)];
#pragma unroll
            for (int qf = 0; qf < 2; ++qf)
              oacc[df][qf] = MFMA(vf, pb[qf], oacc[df][qf]);
          }
        }
        __builtin_amdgcn_s_setprio(0);
      }

      if (kt + 1 < nt) WRITEKV(cur ^ 1);   // vmcnt wait lands here, hidden
    }

    // epilogue: O[b][t][h][d] fp16
#pragma unroll
    for (int qf = 0; qf < 2; ++qf) {
      const float inv = 1.0f / l_[qf];
      const int t = qrow + qf * 16 + q16;
#pragma unroll
      for (int df = 0; df < 8; ++df) {
        const f32x4 v = oacc[df][qf];
        ushort4 o;
        o.x = f2h(v[0] * inv); o.y = f2h(v[1] * inv);
        o.z = f2h(v[2] * inv); o.w = f2h(v[3] * inv);
        *(ushort4*)(O + headbase + (size_t)t * Dc + df * 16 + g * 4) = o;
      }
    }
  }
#undef LOADKV
#undef WRITEKV
}

extern "C" void kernel_launch(void* const* d_in, const int* in_sizes, int n_in,
                              void* d_out, int out_size, void* d_ws, size_t ws_size,
                              hipStream_t stream) {
  (void)in_sizes; (void)n_in; (void)out_size; (void)ws_size;
  const float* x  = (const float*)d_in[0];
  const float* cs = (const float*)d_in[1];
  const float* sn = (const float*)d_in[2];
  // d_in[3] = mask (unused: causal handled analytically)
  const float* Wq = (const float*)d_in[4];
  const float* Wk = (const float*)d_in[5];
  const float* Wv = (const float*)d_in[6];
  const float* Wo = (const float*)d_in[7];
  float* out = (float*)d_out;

  char* ws = (char*)d_ws;
  const size_t MB = 1024 * 1024;
  ushort* xb  = (ushort*)(ws);            // 32MB x fp16; reused as attn output O
  ushort* wqb = (ushort*)(ws + 32 * MB);
  ushort* wkb = (ushort*)(ws + 40 * MB);
  ushort* wvb = (ushort*)(ws + 48 * MB);
  ushort* wob = (ushort*)(ws + 56 * MB);
  ushort* Qr  = (ushort*)(ws + 64 * MB);  // 32MB each, [B,T,H,128] fp16
  ushort* Kr  = (ushort*)(ws + 96 * MB);
  ushort* Vr  = (ushort*)(ws + 128 * MB); // end: 160MB

  cvt<<<16384, 256, 0, stream>>>(x, xb, 4194304);
  cvt<<<4096, 256, 0, stream>>>(Wq, wqb, 1048576);
  cvt<<<4096, 256, 0, stream>>>(Wk, wkb, 1048576);
  cvt<<<4096, 256, 0, stream>>>(Wv, wvb, 1048576);
  cvt<<<4096, 256, 0, stream>>>(Wo, wob, 1048576);

  const dim3 gg(16, 64);
  gemm_bt<ushort><<<gg, 256, 0, stream>>>(xb, wqb, Qr);
  gemm_bt<ushort><<<gg, 256, 0, stream>>>(xb, wkb, Kr);
  gemm_bt<ushort><<<gg, 256, 0, stream>>>(xb, wvb, Vr);

  rope<<<8192, 256, 0, stream>>>(Qr, cs, sn);
  rope<<<8192, 256, 0, stream>>>(Kr, cs, sn);

  attn<<<dim3(8, 64), 256, 0, stream>>>(Qr, Kr, Vr, xb);

  gemm_bt<float><<<gg, 256, 0, stream>>>(xb, wob, out);
}

// Round 3
// 731.528 us; speedup vs baseline: 1.1366x; 1.0949x over previous
//
#include <hip/hip_runtime.h>
#include <hip/hip_bf16.h>

#define DEV static __device__ __forceinline__

typedef __attribute__((ext_vector_type(8))) _Float16 half8;   // A/B frag: 8 fp16 = 4 VGPR
typedef __attribute__((ext_vector_type(4))) float f32x4;      // C/D frag

constexpr int Bc = 4, Tc = 2048, Dc = 2048, Hc = 16;          // HD = 128

DEV ushort f2h(float f) { _Float16 h = (_Float16)f; return __builtin_bit_cast(ushort, h); }
DEV float  h2f(ushort u) { return (float)__builtin_bit_cast(_Float16, u); }

DEV f32x4 MFMA(half8 a, half8 b, f32x4 c) {
  return __builtin_amdgcn_mfma_f32_16x16x32_f16(a, b, c, 0, 0, 0);
}

DEV void async_cp16(void* lds, const void* g) {
  __builtin_amdgcn_global_load_lds((const __attribute__((address_space(1))) void*)g,
                                   (__attribute__((address_space(3))) void*)lds,
                                   16, 0, 0);
}

// ---------------- f32 -> fp16 convert ----------------
__global__ __launch_bounds__(256) void cvt(const float* __restrict__ in,
                                           ushort* __restrict__ out, int n4) {
  const int i = blockIdx.x * 256 + threadIdx.x;
  if (i >= n4) return;
  const float4 v = ((const float4*)in)[i];
  ushort4 o;
  o.x = f2h(v.x); o.y = f2h(v.y); o.z = f2h(v.z); o.w = f2h(v.w);
  ((ushort4*)out)[i] = o;
}

// ---------------- GEMM: C[m][n] = sum_k A[m][k] * W[n][k] ----------------
// 128x128 tile, BK=32, 4 waves (2x2), global_load_lds staging, 16 MFMA/K-step.
template <typename OutT>
__global__ __launch_bounds__(256) void gemm_bt(const ushort* __restrict__ A,
                                               const ushort* __restrict__ Bw,
                                               OutT* __restrict__ C) {
  __shared__ ushort As[128 * 32];
  __shared__ ushort Bs[128 * 32];
  const int tid = threadIdx.x;
  const int lane = tid & 63, wid = tid >> 6;
  const int g = lane >> 4, q16 = lane & 15;
  const int wm = wid >> 1, wn = wid & 1;
  const int bm = blockIdx.y, bn = blockIdx.x;
  const ushort* Ab = A + (size_t)bm * 128 * Dc;
  const ushort* Bb = Bw + (size_t)bn * 128 * Dc;

  f32x4 acc[4][4] = {};

  for (int k0 = 0; k0 < Dc; k0 += 32) {
    __syncthreads();
#pragma unroll
    for (int q = 0; q < 2; ++q) {
      const int c = q * 256 + tid;
      const int row = c >> 2, col = (c & 3) << 3;
      const int ldsbase = (q * 256 + wid * 64) * 8;
      async_cp16(&As[ldsbase], Ab + (size_t)row * Dc + k0 + col);
      async_cp16(&Bs[ldsbase], Bb + (size_t)row * Dc + k0 + col);
    }
    __syncthreads();
    half8 a[4], b[4];
#pragma unroll
    for (int i = 0; i < 4; ++i)
      a[i] = *(const half8*)&As[(wm * 64 + i * 16 + q16) * 32 + g * 8];
#pragma unroll
    for (int j = 0; j < 4; ++j)
      b[j] = *(const half8*)&Bs[(wn * 64 + j * 16 + q16) * 32 + g * 8];
#pragma unroll
    for (int i = 0; i < 4; ++i)
#pragma unroll
      for (int j = 0; j < 4; ++j)
        acc[i][j] = MFMA(a[i], b[j], acc[i][j]);
  }

  const int m00 = bm * 128 + wm * 64 + g * 4;
  const int n0 = bn * 128 + wn * 64 + q16;
#pragma unroll
  for (int i = 0; i < 4; ++i)
#pragma unroll
    for (int j = 0; j < 4; ++j) {
      const int m0 = m00 + i * 16;
      const int n = n0 + j * 16;
#pragma unroll
      for (int r = 0; r < 4; ++r) {
        const float v = acc[i][j][r];
        if constexpr (sizeof(OutT) == 2)
          C[(size_t)(m0 + r) * Dc + n] = (OutT)f2h(v);
        else
          C[(size_t)(m0 + r) * Dc + n] = (OutT)v;
      }
    }
}

// ---------------- RoPE in-place on [B,T,H,128] fp16 ----------------
__global__ __launch_bounds__(256) void rope(ushort* __restrict__ X,
                                            const float* __restrict__ cs,
                                            const float* __restrict__ sn) {
  const int tid = blockIdx.x * 256 + threadIdx.x;
  const int row = tid >> 4;
  const int jq = (tid & 15) << 2;
  const int t = (row >> 4) & (Tc - 1);
  ushort* base = X + (size_t)row * 128;
  const ushort4 lo = *(const ushort4*)(base + jq);
  const ushort4 hi = *(const ushort4*)(base + 64 + jq);
  const float4 c4 = *(const float4*)(cs + t * 128 + jq);
  const float4 s4 = *(const float4*)(sn + t * 128 + jq);
  const float xl[4] = {h2f(lo.x), h2f(lo.y), h2f(lo.z), h2f(lo.w)};
  const float xh[4] = {h2f(hi.x), h2f(hi.y), h2f(hi.z), h2f(hi.w)};
  const float cc[4] = {c4.x, c4.y, c4.z, c4.w};
  const float ss[4] = {s4.x, s4.y, s4.z, s4.w};
  ushort4 olo, ohi;
  ushort* po = (ushort*)&olo;
  ushort* ph = (ushort*)&ohi;
#pragma unroll
  for (int k = 0; k < 4; ++k) {
    po[k] = f2h(xl[k] * cc[k] - xh[k] * ss[k]);
    ph[k] = f2h(xh[k] * cc[k] + xl[k] * ss[k]);
  }
  *(ushort4*)(base + jq) = olo;
  *(ushort4*)(base + 64 + jq) = ohi;
}

// ---------------- causal flash attention (paired q-tiles, dbuf LDS) ------
// grid (8, 64): block handles q-tiles {15-bx, bx} -> uniform 36 kv-tile
// iterations; 512 blocks = 2 blocks/CU (LDS-capped). K staged direct-to-LDS
// via global_load_lds with PRE-SWIZZLED source (linear dest + inverse-XOR'd
// source granule + XOR'd read = rule #21 both-sides). V reg-staged transpose,
// T14 split. No VGPR cap (LDS caps occupancy; a reg cap just forces spills).
__global__ __launch_bounds__(256) void attn(const ushort* __restrict__ Q,
                                            const ushort* __restrict__ K,
                                            const ushort* __restrict__ V,
                                            ushort* __restrict__ O) {
  __shared__ ushort Ks[2][64 * 128];   // [kv][d], XOR-swizzled (granule ^= kv&7)
  __shared__ ushort Vt[2][128 * 64];   // [d][kv], XOR-swizzled rows
  __shared__ ushort Pt[4][32 * 64];    // per-wave [q][kv]

  const int tid = threadIdx.x;
  const int lane = tid & 63, wid = tid >> 6;
  const int g = lane >> 4, q16 = lane & 15;
  const int bh = blockIdx.y;
  const int b = bh >> 4, h = bh & 15;
  const size_t headbase = ((size_t)b * Tc * Hc + h) * 128;  // t-stride = 2048
  const float SCL2 = 0.12751743f;      // log2(e)/sqrt(128)

  uint4 vreg[4];

  // K tile kt -> Ks[buf] direct to LDS; source granule pre-swizzled so that
  // linear LDS layout equals the swizzled layout the reader expects.
#define ISSUEK(KT, BUF) do {                                                   \
    const ushort* Kb_ = K + headbase + (size_t)(KT) * 64 * Dc;                 \
    _Pragma("unroll") for (int i_ = 0; i_ < 4; ++i_) {                         \
      const int c_ = i_ * 256 + tid;                                           \
      const int kv_ = c_ >> 4, gl_ = c_ & 15;                                  \
      async_cp16(&Ks[BUF][(i_ * 256 + wid * 64) * 8],                          \
                 Kb_ + (size_t)kv_ * Dc + ((gl_ ^ (kv_ & 7)) << 3));           \
    }                                                                          \
  } while (0)

#define LOADV(KT) do {                                                         \
    const ushort* Vb_ = V + headbase + (size_t)(KT) * 64 * Dc;                 \
    _Pragma("unroll") for (int i_ = 0; i_ < 2; ++i_) {                         \
      const int kvp_ = i_ * 16 + (lane >> 2);                                  \
      const int dc_ = wid * 4 + (lane & 3);                                    \
      const ushort* p0_ = Vb_ + (size_t)(2 * kvp_) * Dc + dc_ * 8;             \
      vreg[2 * i_] = *(const uint4*)p0_;                                       \
      vreg[2 * i_ + 1] = *(const uint4*)(p0_ + Dc);                            \
    }                                                                          \
  } while (0)

#define WRITEV(BUF) do {                                                       \
    _Pragma("unroll") for (int i_ = 0; i_ < 2; ++i_) {                         \
      const int kvp_ = i_ * 16 + (lane >> 2);                                  \
      const int dc_ = wid * 4 + (lane & 3);                                    \
      const ushort* e0_ = (const ushort*)&vreg[2 * i_];                        \
      const ushort* e1_ = (const ushort*)&vreg[2 * i_ + 1];                    \
      _Pragma("unroll") for (int j_ = 0; j_ < 8; ++j_) {                       \
        const int d_ = dc_ * 8 + j_;                                           \
        const unsigned w_ = (unsigned)e0_[j_] | ((unsigned)e1_[j_] << 16);     \
        *(unsigned*)&Vt[BUF][(d_ * 64 + 2 * kvp_) ^ ((d_ & 7) << 3)] = w_;     \
      }                                                                        \
    }                                                                          \
  } while (0)

#pragma unroll 1
  for (int half = 0; half < 2; ++half) {
    const int q0 = (half ? (int)blockIdx.x : 15 - (int)blockIdx.x) * 128;
    const int qrow = q0 + wid * 32;
    const int nt = q0 / 64 + 2;

    // Q fragments (B-op: col=q=lane&15, k=d=g*8+j)
    half8 qreg[2][4];
#pragma unroll
    for (int qf = 0; qf < 2; ++qf)
#pragma unroll
      for (int ds = 0; ds < 4; ++ds)
        qreg[qf][ds] = *(const half8*)(Q + headbase +
                       (size_t)(qrow + qf * 16 + q16) * Dc + ds * 32 + g * 8);

    f32x4 oacc[8][2] = {};             // O^T frags: row=d (g*4+r), col=q
    float m_[2] = {-1e30f, -1e30f};
    float l_[2] = {0.f, 0.f};

    __builtin_amdgcn_s_barrier();      // prior half done reading all LDS bufs
    __builtin_amdgcn_sched_barrier(0);
    ISSUEK(0, 0);
    LOADV(0);
    WRITEV(0);                         // compiler waits vmcnt for vreg here

#pragma unroll 1
    for (int kt = 0; kt < nt; ++kt) {
      const int cur = kt & 1;
      const int kv0 = kt * 64;
      // K async loads into Ks[cur] landed; Vt[cur] ds_writes visible:
      asm volatile("s_waitcnt vmcnt(0) lgkmcnt(0)" ::: "memory");
      __builtin_amdgcn_s_barrier();
      __builtin_amdgcn_sched_barrier(0);
      // buf[cur^1] now provably free -> prefetch next tile
      if (kt + 1 < nt) {
        ISSUEK(kt + 1, cur ^ 1);
        LOADV(kt + 1);
      }

      if (kv0 <= qrow + 31) {
        const ushort* Ksb = Ks[cur];
        const ushort* Vtb = Vt[cur];
        // S^T = K Q^T
        f32x4 s[4][2] = {};
        __builtin_amdgcn_s_setprio(1);
#pragma unroll
        for (int ds = 0; ds < 4; ++ds) {
          half8 kf[4];
#pragma unroll
          for (int kvf = 0; kvf < 4; ++kvf) {
            const int kv = kvf * 16 + q16;
            kf[kvf] = *(const half8*)&Ksb[(kv * 128 + ds * 32 + g * 8) ^ ((kv & 7) << 3)];
          }
#pragma unroll
          for (int kvf = 0; kvf < 4; ++kvf)
#pragma unroll
            for (int qf = 0; qf < 2; ++qf)
              s[kvf][qf] = MFMA(kf[kvf], qreg[qf][ds], s[kvf][qf]);
        }
        __builtin_amdgcn_s_setprio(0);
        // causal mask + running max (q = lane&15 + 16*qf; kv = kv0+kvf*16+g*4+r)
        const bool notfull = (kv0 + 63) > qrow;
        float pmax[2] = {-1e30f, -1e30f};
#pragma unroll
        for (int qf = 0; qf < 2; ++qf) {
          const int qg = qrow + qf * 16 + q16;
#pragma unroll
          for (int kvf = 0; kvf < 4; ++kvf)
#pragma unroll
            for (int r = 0; r < 4; ++r) {
              float v = s[kvf][qf][r];
              if (notfull && (kv0 + kvf * 16 + g * 4 + r) > qg) v = -1e30f;
              s[kvf][qf][r] = v;
              pmax[qf] = fmaxf(pmax[qf], v);
            }
        }
#pragma unroll
        for (int qf = 0; qf < 2; ++qf) {
          pmax[qf] = fmaxf(pmax[qf], __shfl_xor(pmax[qf], 16));
          pmax[qf] = fmaxf(pmax[qf], __shfl_xor(pmax[qf], 32));
        }
        float alpha[2];
        ushort* Ptw = Pt[wid];
#pragma unroll
        for (int qf = 0; qf < 2; ++qf) {
          const float mn = fmaxf(m_[qf], pmax[qf]);
          alpha[qf] = __builtin_exp2f((m_[qf] - mn) * SCL2);
          m_[qf] = mn;
          float lsum = 0.f;
#pragma unroll
          for (int kvf = 0; kvf < 4; ++kvf) {
            const float p0 = __builtin_exp2f((s[kvf][qf][0] - mn) * SCL2);
            const float p1 = __builtin_exp2f((s[kvf][qf][1] - mn) * SCL2);
            const float p2 = __builtin_exp2f((s[kvf][qf][2] - mn) * SCL2);
            const float p3 = __builtin_exp2f((s[kvf][qf][3] - mn) * SCL2);
            lsum += (p0 + p1) + (p2 + p3);
            uint2 pk;
            pk.x = (unsigned)f2h(p0) | ((unsigned)f2h(p1) << 16);
            pk.y = (unsigned)f2h(p2) | ((unsigned)f2h(p3) << 16);
            const int row = qf * 16 + q16;
            *(uint2*)&Ptw[(row * 64 + kvf * 16 + g * 4) ^ ((row & 7) << 3)] = pk;
          }
          lsum += __shfl_xor(lsum, 16);
          lsum += __shfl_xor(lsum, 32);
          l_[qf] = l_[qf] * alpha[qf] + lsum;
        }
#pragma unroll
        for (int df = 0; df < 8; ++df)
#pragma unroll
          for (int qf = 0; qf < 2; ++qf)
            oacc[df][qf] *= alpha[qf];
        // O^T += V^T P^T
        __builtin_amdgcn_s_setprio(1);
#pragma unroll
        for (int c = 0; c < 2; ++c) {
          half8 pb[2];
#pragma unroll
          for (int qf = 0; qf < 2; ++qf) {
            const int row = qf * 16 + q16;
            pb[qf] = *(const half8*)&Ptw[(row * 64 + c * 32 + g * 8) ^ ((row & 7) << 3)];
          }
#pragma unroll
          for (int df = 0; df < 8; ++df) {
            const int d = df * 16 + q16;
            const half8 vf = *(const half8*)&Vtb[(d * 64 + c * 32 + g * 8) ^ ((d & 7) << 3)];
#pragma unroll
            for (int qf = 0; qf < 2; ++qf)
              oacc[df][qf] = MFMA(vf, pb[qf], oacc[df][qf]);
          }
        }
        __builtin_amdgcn_s_setprio(0);
      }

      if (kt + 1 < nt) WRITEV(cur ^ 1);   // vreg vmcnt wait lands here, hidden
    }

    // epilogue: O[b][t][h][d] fp16
#pragma unroll
    for (int qf = 0; qf < 2; ++qf) {
      const float inv = 1.0f / l_[qf];
      const int t = qrow + qf * 16 + q16;
#pragma unroll
      for (int df = 0; df < 8; ++df) {
        const f32x4 v = oacc[df][qf];
        ushort4 o;
        o.x = f2h(v[0] * inv); o.y = f2h(v[1] * inv);
        o.z = f2h(v[2] * inv); o.w = f2h(v[3] * inv);
        *(ushort4*)(O + headbase + (size_t)t * Dc + df * 16 + g * 4) = o;
      }
    }
  }
#undef ISSUEK
#undef LOADV
#undef WRITEV
}

extern "C" void kernel_launch(void* const* d_in, const int* in_sizes, int n_in,
                              void* d_out, int out_size, void* d_ws, size_t ws_size,
                              hipStream_t stream) {
  (void)in_sizes; (void)n_in; (void)out_size; (void)ws_size;
  const float* x  = (const float*)d_in[0];
  const float* cs = (const float*)d_in[1];
  const float* sn = (const float*)d_in[2];
  // d_in[3] = mask (unused: causal handled analytically)
  const float* Wq = (const float*)d_in[4];
  const float* Wk = (const float*)d_in[5];
  const float* Wv = (const float*)d_in[6];
  const float* Wo = (const float*)d_in[7];
  float* out = (float*)d_out;

  char* ws = (char*)d_ws;
  const size_t MB = 1024 * 1024;
  ushort* xb  = (ushort*)(ws);            // 32MB x fp16; reused as attn output O
  ushort* wqb = (ushort*)(ws + 32 * MB);
  ushort* wkb = (ushort*)(ws + 40 * MB);
  ushort* wvb = (ushort*)(ws + 48 * MB);
  ushort* wob = (ushort*)(ws + 56 * MB);
  ushort* Qr  = (ushort*)(ws + 64 * MB);  // 32MB each, [B,T,H,128] fp16
  ushort* Kr  = (ushort*)(ws + 96 * MB);
  ushort* Vr  = (ushort*)(ws + 128 * MB); // end: 160MB

  cvt<<<16384, 256, 0, stream>>>(x, xb, 4194304);
  cvt<<<4096, 256, 0, stream>>>(Wq, wqb, 1048576);
  cvt<<<4096, 256, 0, stream>>>(Wk, wkb, 1048576);
  cvt<<<4096, 256, 0, stream>>>(Wv, wvb, 1048576);
  cvt<<<4096, 256, 0, stream>>>(Wo, wob, 1048576);

  const dim3 gg(16, 64);
  gemm_bt<ushort><<<gg, 256, 0, stream>>>(xb, wqb, Qr);
  gemm_bt<ushort><<<gg, 256, 0, stream>>>(xb, wkb, Kr);
  gemm_bt<ushort><<<gg, 256, 0, stream>>>(xb, wvb, Vr);

  rope<<<8192, 256, 0, stream>>>(Qr, cs, sn);
  rope<<<8192, 256, 0, stream>>>(Kr, cs, sn);

  attn<<<dim3(8, 64), 256, 0, stream>>>(Qr, Kr, Vr, xb);

  gemm_bt<float><<<gg, 256, 0, stream>>>(xb, wob, out);
}